// Round 1
// baseline (320.659 us; speedup 1.0000x reference)
//
#include <hip/hip_runtime.h>
#include <stdint.h>

typedef unsigned long long u64;

#define N 8192
#define NW 128            // 64-bit words per mask row
#define SORT_THREADS 1024
#define MAX_OUT 256
#define MASK_BYTES ((size_t)N * NW * 8)   // 8 MiB

// ws layout:
//   [0, 8MB)                mask      u64[N][NW]
//   +0      (after mask)    order     int[N]      32 KB
//   +32KB                   s_s       float[N]    32 KB
//   +64KB                   bbox      float4[N]  128 KB
//   +192KB                  area      float[N]    32 KB
//   +224KB                  nvalid    int

// ---------------- Kernel 1: bitonic sort + precompute ----------------
// key = (~score_bits << 32) | idx  → ascending sort == score desc, idx asc
// (scores are non-negative floats, so uint bit pattern is order-preserving;
//  idx tie-break replicates jnp stable argsort)
__global__ __launch_bounds__(SORT_THREADS)
void sort_kernel(const float* __restrict__ score, const float* __restrict__ box,
                 int* __restrict__ order, float* __restrict__ s_s,
                 float4* __restrict__ bbox, float* __restrict__ area,
                 int* __restrict__ nvalid) {
    __shared__ u64 keys[N];   // 64 KB
    const int tid = threadIdx.x;
    for (int i = tid; i < N; i += SORT_THREADS) {
        uint32_t b = __float_as_uint(score[i]);
        keys[i] = ((u64)(~b) << 32) | (uint32_t)i;
    }
    __syncthreads();
    for (int k = 2; k <= N; k <<= 1) {
        for (int j = k >> 1; j > 0; j >>= 1) {
            for (int i = tid; i < N; i += SORT_THREADS) {
                int ixj = i ^ j;
                if (ixj > i) {
                    u64 a = keys[i], c = keys[ixj];
                    bool swap = ((i & k) == 0) ? (a > c) : (a < c);
                    if (swap) { keys[i] = c; keys[ixj] = a; }
                }
            }
            __syncthreads();
        }
    }
    for (int i = tid; i < N; i += SORT_THREADS) {
        u64 kk = keys[i];
        int idx = (int)(uint32_t)(kk & 0xFFFFFFFFull);
        float s = __uint_as_float(~(uint32_t)(kk >> 32));
        order[i] = idx;
        s_s[i] = s;
        float cx = box[idx*16 + 0], cy = box[idx*16 + 1];
        float w  = box[idx*16 + 2], h  = box[idx*16 + 3];
        float hw = w * 0.5f, hh = h * 0.5f;
        float x0 = cx - hw, y0 = cy - hh, x1 = cx + hw, y1 = cy + hh;
        bbox[i] = make_float4(x0, y0, x1, y1);
        area[i] = (x1 - x0) * (y1 - y0);   // replicate ref: area from xyxy
        bool v = (s >= 0.3f);
        if (i == 0 && !v) *nvalid = 0;
        bool vn = false;
        if (i + 1 < N) {
            float sn = __uint_as_float(~(uint32_t)(keys[i+1] >> 32));
            vn = (sn >= 0.3f);
        }
        if (v && !vn) *nvalid = i + 1;   // unique boundary writer (scores sorted desc)
    }
}

// ---------------- Kernel 2: suppression bitmask (upper triangle) ----------------
// grid (128, 32), block 256: w = blockIdx.x (j-word), i = blockIdx.y*256 + tid.
// Computes mask[i][w] only for w >= i/64 and i < nvalid; garbage elsewhere is
// provably harmless (only ORs bits for already-processed positions).
__global__ __launch_bounds__(256)
void mask_kernel(const float4* __restrict__ bbox, const float* __restrict__ area,
                 const int* __restrict__ nvalid_p, u64* __restrict__ mask) {
    const int w = blockIdx.x;
    const int i = blockIdx.y * 256 + threadIdx.x;
    __shared__ float4 jb[64];
    __shared__ float  ja[64];
    if (threadIdx.x < 64) {
        jb[threadIdx.x] = bbox[w * 64 + threadIdx.x];
        ja[threadIdx.x] = area[w * 64 + threadIdx.x];
    }
    __syncthreads();
    const int nv = *nvalid_p;
    if (i >= nv) return;
    if (w < (i >> 6)) return;
    float4 a = bbox[i];
    float  aa = area[i];
    u64 bits = 0;
    #pragma unroll 8
    for (int jj = 0; jj < 64; ++jj) {
        float4 b = jb[jj];
        float lx = fmaxf(a.x, b.x), ly = fmaxf(a.y, b.y);
        float rx = fminf(a.z, b.z), ry = fminf(a.w, b.w);
        float ww = fmaxf(rx - lx, 0.0f), hh = fmaxf(ry - ly, 0.0f);
        float inter = ww * hh;
        float denom = ((aa + ja[jj]) - inter) + 1e-9f;  // exact ref op order
        float iou = inter / denom;                       // IEEE div, matches np
        bits |= ((u64)(iou > 0.3f)) << jj;
    }
    mask[(size_t)i * NW + w] = bits;
}

// ---------------- Kernel 3: serial greedy pass (single wave) + output ----------------
// Lane l owns remv words 2l, 2l+1. Per 64-box block: 1 column-word load/lane,
// 1 shfl for the block's remv word, ballot-based in-block triangle resolve
// (symmetry: tile column == tile row), then OR kept rows into remv.
__global__ __launch_bounds__(64)
void nms_kernel(const u64* __restrict__ mask, const float* __restrict__ s_s,
                const int* __restrict__ order, const float* __restrict__ box,
                const int* __restrict__ nvalid_p, float* __restrict__ out) {
    const int lane = threadIdx.x;
    const int nv = *nvalid_p;
    __shared__ int kpos[MAX_OUT];
    u64 remv0 = 0, remv1 = 0;
    int kcount = 0;
    const int nblk = (nv + 63) >> 6;
    for (int b = 0; b < nblk && kcount < MAX_OUT; ++b) {
        const int base = b << 6;
        u64 col = mask[(size_t)(base + lane) * NW + b];
        // broadcast remv word b from its owner lane
        u64 sel = (b & 1) ? remv1 : remv0;
        unsigned int lo = __shfl((int)(unsigned int)sel, b >> 1);
        unsigned int hi = __shfl((int)(unsigned int)(sel >> 32), b >> 1);
        u64 rw = ((u64)hi << 32) | lo;
        int rem = nv - base;
        u64 validm = (rem >= 64) ? ~0ull : ((1ull << rem) - 1ull);
        u64 todo = validm & ~rw;
        while (todo) {
            int l = (int)__builtin_ctzll(todo);
            // keep box base+l
            u64 row_l = __ballot(((col >> l) & 1ull) != 0);  // in-tile row via symmetry
            if (lane == 0) kpos[kcount] = base + l;
            kcount++;
            const u64* rp = mask + (size_t)(base + l) * NW + 2 * lane;
            remv0 |= rp[0];
            remv1 |= rp[1];
            todo &= ~row_l;
            todo &= ~(1ull << l);   // self-IoU bit may be 0 for zero-area boxes
            if (kcount >= MAX_OUT) break;
        }
    }
    __syncthreads();
    // outputs: [score 256][box 256*16][valid 256], all float32
    float* out_score = out;
    float* out_box   = out + MAX_OUT;
    float* out_valid = out + MAX_OUT + MAX_OUT * 16;
    const float4* box4 = (const float4*)box;
    float4* ob4 = (float4*)out_box;
    for (int t = lane; t < MAX_OUT; t += 64) {
        if (t < kcount) {
            int p = kpos[t];
            out_score[t] = s_s[p];
            out_valid[t] = 1.0f;
            int oi = order[p];
            #pragma unroll
            for (int q = 0; q < 4; ++q) ob4[t * 4 + q] = box4[oi * 4 + q];
        } else {
            out_score[t] = 0.0f;
            out_valid[t] = 0.0f;
            float4 z = make_float4(0.f, 0.f, 0.f, 0.f);
            #pragma unroll
            for (int q = 0; q < 4; ++q) ob4[t * 4 + q] = z;
        }
    }
}

extern "C" void kernel_launch(void* const* d_in, const int* in_sizes, int n_in,
                              void* d_out, int out_size, void* d_ws, size_t ws_size,
                              hipStream_t stream) {
    const float* score = (const float*)d_in[0];   // (8192,1) f32
    const float* box   = (const float*)d_in[1];   // (8192,16) f32
    char* ws = (char*)d_ws;
    u64*    mask   = (u64*)ws;
    int*    order  = (int*)   (ws + MASK_BYTES);
    float*  s_s    = (float*) (ws + MASK_BYTES + 32768);
    float4* bbox   = (float4*)(ws + MASK_BYTES + 65536);
    float*  area   = (float*) (ws + MASK_BYTES + 65536 + 131072);
    int*    nvalid = (int*)   (ws + MASK_BYTES + 65536 + 131072 + 32768);

    sort_kernel<<<1, SORT_THREADS, 0, stream>>>(score, box, order, s_s, bbox, area, nvalid);
    mask_kernel<<<dim3(128, 32), 256, 0, stream>>>(bbox, area, nvalid, mask);
    nms_kernel<<<1, 64, 0, stream>>>(mask, s_s, order, box, nvalid, (float*)d_out);
}

// Round 2
// 179.816 us; speedup vs baseline: 1.7833x; 1.7833x over previous
//
#include <hip/hip_runtime.h>
#include <stdint.h>

typedef unsigned long long u64;

#define N 8192
#define NW 128            // 64-bit words per mask row
#define MAX_OUT 256
#define MASK_BYTES ((size_t)N * NW * 8)   // 8 MiB

// ws layout:
//   [0, 8MB)    mask u64[N][NW]
//     overlap (dead before mask_kernel writes):
//       ws+0      keys u64[N]   (64 KB)   written by build_keys, read by rank
//       ws+64KB   rank int[N]   (32 KB)   zeroed by build_keys, atomicAdd by rank, read by scatter
//   +8MB        order  int[N]     32 KB
//   +32KB       s_s    float[N]   32 KB
//   +64KB       bbox   float4[N] 128 KB
//   +192KB      area   float[N]   32 KB
//   +224KB      nvalid int

// ---------------- Kernel A: build sort keys + zero ranks ----------------
// key = (~score_bits << 32) | idx → ascending == score desc, idx asc (stable).
// Scores non-negative → uint bit pattern order-preserving; keys unique (idx).
__global__ __launch_bounds__(256)
void build_keys_kernel(const float* __restrict__ score, u64* __restrict__ keys,
                       int* __restrict__ rank) {
    int i = blockIdx.x * 256 + threadIdx.x;
    uint32_t b = __float_as_uint(score[i]);
    keys[i] = ((u64)(~b) << 32) | (uint32_t)i;
    rank[i] = 0;
}

// ---------------- Kernel NV: nvalid = count(score >= 0.3) ----------------
// Sorted desc ⇒ valid is a prefix; its length is just the global count.
__global__ __launch_bounds__(1024)
void count_valid_kernel(const float* __restrict__ score, int* __restrict__ nvalid) {
    __shared__ int part[16];
    int tid = threadIdx.x;
    int c = 0;
    for (int i = tid; i < N; i += 1024) c += (score[i] >= 0.3f) ? 1 : 0;
    for (int off = 32; off; off >>= 1) c += __shfl_down(c, off);
    if ((tid & 63) == 0) part[tid >> 6] = c;
    __syncthreads();
    if (tid == 0) { int t = 0; for (int w = 0; w < 16; ++w) t += part[w]; *nvalid = t; }
}

// ---------------- Kernel B: rank = #{j : key[j] < key[i]} ----------------
// grid (32 i-chunks, 8 j-chunks) × 256. j-chunk staged in LDS; all threads
// scan the same j sequence → pure LDS broadcast, no bank conflicts.
__global__ __launch_bounds__(256)
void rank_kernel(const u64* __restrict__ keys, int* __restrict__ rank) {
    __shared__ u64 kj[1024];
    const int tid = threadIdx.x;
    const int jbase = blockIdx.y * 1024;
    for (int t = tid; t < 1024; t += 256) kj[t] = keys[jbase + t];
    __syncthreads();
    const int i = blockIdx.x * 256 + tid;
    const u64 ki = keys[i];
    int c = 0;
    #pragma unroll 8
    for (int j = 0; j < 1024; ++j) c += (kj[j] < ki) ? 1 : 0;
    atomicAdd(&rank[i], c);
}

// ---------------- Kernel C: scatter to sorted order + precompute ----------------
__global__ __launch_bounds__(256)
void scatter_kernel(const float* __restrict__ score, const float* __restrict__ box,
                    const int* __restrict__ rank, int* __restrict__ order,
                    float* __restrict__ s_s, float4* __restrict__ bbox,
                    float* __restrict__ area) {
    int i = blockIdx.x * 256 + threadIdx.x;
    int r = rank[i];
    float s = score[i];
    order[r] = i;
    s_s[r] = s;
    float cx = box[i*16 + 0], cy = box[i*16 + 1];
    float w  = box[i*16 + 2], h  = box[i*16 + 3];
    float hw = w * 0.5f, hh = h * 0.5f;
    float x0 = cx - hw, y0 = cy - hh, x1 = cx + hw, y1 = cy + hh;
    bbox[r] = make_float4(x0, y0, x1, y1);
    area[r] = (x1 - x0) * (y1 - y0);   // replicate ref: area from xyxy
}

// ---------------- Kernel 2: suppression bitmask (upper triangle) ----------------
__global__ __launch_bounds__(256)
void mask_kernel(const float4* __restrict__ bbox, const float* __restrict__ area,
                 const int* __restrict__ nvalid_p, u64* __restrict__ mask) {
    const int w = blockIdx.x;
    const int i = blockIdx.y * 256 + threadIdx.x;
    __shared__ float4 jb[64];
    __shared__ float  ja[64];
    if (threadIdx.x < 64) {
        jb[threadIdx.x] = bbox[w * 64 + threadIdx.x];
        ja[threadIdx.x] = area[w * 64 + threadIdx.x];
    }
    __syncthreads();
    const int nv = *nvalid_p;
    if (i >= nv) return;
    if (w < (i >> 6)) return;
    float4 a = bbox[i];
    float  aa = area[i];
    u64 bits = 0;
    #pragma unroll 8
    for (int jj = 0; jj < 64; ++jj) {
        float4 b = jb[jj];
        float lx = fmaxf(a.x, b.x), ly = fmaxf(a.y, b.y);
        float rx = fminf(a.z, b.z), ry = fminf(a.w, b.w);
        float ww = fmaxf(rx - lx, 0.0f), hh = fmaxf(ry - ly, 0.0f);
        float inter = ww * hh;
        float denom = ((aa + ja[jj]) - inter) + 1e-9f;  // exact ref op order
        float iou = inter / denom;                       // IEEE div, matches np
        bits |= ((u64)(iou > 0.3f)) << jj;
    }
    mask[(size_t)i * NW + w] = bits;
}

// ---------------- Kernel 3: serial greedy pass (single wave) + output ----------------
// Lane l owns remv words 2l,2l+1. Per block: prefetched column word, remv
// broadcast via shfl, ballot-only in-block resolve (row via symmetry), then
// batched (4-wide) row-OR loads — row ORs only affect FUTURE blocks so they
// are off the critical path of the in-block while loop.
__global__ __launch_bounds__(64)
void nms_kernel(const u64* __restrict__ mask, const float* __restrict__ s_s,
                const int* __restrict__ order, const float* __restrict__ box,
                const int* __restrict__ nvalid_p, float* __restrict__ out) {
    const int lane = threadIdx.x;
    const int nv = *nvalid_p;
    __shared__ int kpos[MAX_OUT];
    u64 remv0 = 0, remv1 = 0;
    int kcount = 0;
    const int nblk = (nv + 63) >> 6;
    u64 col_cur = 0;
    if (nblk > 0) col_cur = mask[(size_t)lane * NW + 0];
    for (int b = 0; b < nblk && kcount < MAX_OUT; ++b) {
        const int base = b << 6;
        u64 col = col_cur;
        u64 col_next = 0;
        if (b + 1 < nblk)
            col_next = mask[(size_t)(base + 64 + lane) * NW + (b + 1)];  // prefetch
        // broadcast remv word b from its owner lane
        u64 sel = (b & 1) ? remv1 : remv0;
        unsigned int lo = __shfl((int)(unsigned int)sel, b >> 1);
        unsigned int hi = __shfl((int)(unsigned int)(sel >> 32), b >> 1);
        u64 rw = ((u64)hi << 32) | lo;
        int rem = nv - base;
        u64 validm = (rem >= 64) ? ~0ull : ((1ull << rem) - 1ull);
        u64 todo = validm & ~rw;
        u64 km = 0;   // kept-in-this-block bitmask (uniform across lanes)
        while (todo) {
            int l = (int)__builtin_ctzll(todo);
            u64 row_l = __ballot(((col >> l) & 1ull) != 0);  // in-tile row via symmetry
            if (lane == 0) kpos[kcount] = base + l;
            km |= (1ull << l);
            kcount++;
            todo &= ~row_l;
            todo &= ~(1ull << l);
            if (kcount >= MAX_OUT) break;
        }
        // batched row ORs (affect future blocks only)
        while (km) {
            int l0 = (int)__builtin_ctzll(km); km &= km - 1;
            int l1 = -1, l2 = -1, l3 = -1;
            if (km) { l1 = (int)__builtin_ctzll(km); km &= km - 1; }
            if (km) { l2 = (int)__builtin_ctzll(km); km &= km - 1; }
            if (km) { l3 = (int)__builtin_ctzll(km); km &= km - 1; }
            const u64* r0 = mask + (size_t)(base + l0) * NW + 2 * lane;
            u64 a0 = r0[0], b0 = r0[1];
            u64 a1 = 0, b1 = 0, a2 = 0, b2 = 0, a3 = 0, b3 = 0;
            if (l1 >= 0) { const u64* r1 = mask + (size_t)(base + l1) * NW + 2 * lane; a1 = r1[0]; b1 = r1[1]; }
            if (l2 >= 0) { const u64* r2 = mask + (size_t)(base + l2) * NW + 2 * lane; a2 = r2[0]; b2 = r2[1]; }
            if (l3 >= 0) { const u64* r3 = mask + (size_t)(base + l3) * NW + 2 * lane; a3 = r3[0]; b3 = r3[1]; }
            remv0 |= a0 | a1 | a2 | a3;
            remv1 |= b0 | b1 | b2 | b3;
        }
        col_cur = col_next;
    }
    __syncthreads();
    // outputs: [score 256][box 256*16][valid 256], all float32
    float* out_score = out;
    float* out_box   = out + MAX_OUT;
    float* out_valid = out + MAX_OUT + MAX_OUT * 16;
    const float4* box4 = (const float4*)box;
    float4* ob4 = (float4*)out_box;
    for (int t = lane; t < MAX_OUT; t += 64) {
        if (t < kcount) {
            int p = kpos[t];
            out_score[t] = s_s[p];
            out_valid[t] = 1.0f;
            int oi = order[p];
            #pragma unroll
            for (int q = 0; q < 4; ++q) ob4[t * 4 + q] = box4[oi * 4 + q];
        } else {
            out_score[t] = 0.0f;
            out_valid[t] = 0.0f;
            float4 z = make_float4(0.f, 0.f, 0.f, 0.f);
            #pragma unroll
            for (int q = 0; q < 4; ++q) ob4[t * 4 + q] = z;
        }
    }
}

extern "C" void kernel_launch(void* const* d_in, const int* in_sizes, int n_in,
                              void* d_out, int out_size, void* d_ws, size_t ws_size,
                              hipStream_t stream) {
    const float* score = (const float*)d_in[0];   // (8192,1) f32
    const float* box   = (const float*)d_in[1];   // (8192,16) f32
    char* ws = (char*)d_ws;
    u64*    mask   = (u64*)ws;
    // overlap region (dead before mask_kernel):
    u64*    keys   = (u64*)ws;                    // 64 KB
    int*    rank   = (int*)(ws + 65536);          // 32 KB
    // persistent region:
    int*    order  = (int*)   (ws + MASK_BYTES);
    float*  s_s    = (float*) (ws + MASK_BYTES + 32768);
    float4* bbox   = (float4*)(ws + MASK_BYTES + 65536);
    float*  area   = (float*) (ws + MASK_BYTES + 65536 + 131072);
    int*    nvalid = (int*)   (ws + MASK_BYTES + 65536 + 131072 + 32768);

    build_keys_kernel<<<32, 256, 0, stream>>>(score, keys, rank);
    count_valid_kernel<<<1, 1024, 0, stream>>>(score, nvalid);
    rank_kernel<<<dim3(32, 8), 256, 0, stream>>>(keys, rank);
    scatter_kernel<<<32, 256, 0, stream>>>(score, box, rank, order, s_s, bbox, area);
    mask_kernel<<<dim3(128, 32), 256, 0, stream>>>(bbox, area, nvalid, mask);
    nms_kernel<<<1, 64, 0, stream>>>(mask, s_s, order, box, nvalid, (float*)d_out);
}